// Round 8
// baseline (114887.305 us; speedup 1.0000x reference)
//
#include <hip/hip_runtime.h>
#include <math.h>

#define NLFULL 504
#define REAL_NL 500
#define BATCH 2048
#define NZ 50
#define NC 21
#define GHID 512
#define EPSB 1e-5f
#define LO_SCALE 2048.0f
#define INV_LO (1.0f / 2048.0f)

typedef __attribute__((ext_vector_type(4))) float f32x4;
typedef __attribute__((ext_vector_type(8))) _Float16 half8;

__device__ __forceinline__ void split2(float x, _Float16& hi, _Float16& lo) {
    hi = (_Float16)x;
    lo = (_Float16)((x - (float)hi) * LO_SCALE);
}

// =============================== upsample ==================================
__global__ __launch_bounds__(512) void upsample_kernel(
    const float* __restrict__ z, const float* __restrict__ dW, const float* __restrict__ db,
    const float* __restrict__ W0, const float* __restrict__ g0, const float* __restrict__ bb0,
    const float* __restrict__ m0, const float* __restrict__ v0, const float* __restrict__ al0,
    const float* __restrict__ W1, const float* __restrict__ g1, const float* __restrict__ bb1,
    const float* __restrict__ m1, const float* __restrict__ v1, const float* __restrict__ al1,
    const float* __restrict__ W2, const float* __restrict__ g2, const float* __restrict__ bb2,
    const float* __restrict__ m2, const float* __restrict__ v2, const float* __restrict__ al2,
    float* __restrict__ hseq)
{
    __shared__ float bufA[5712];
    __shared__ float bufB[5544];
    __shared__ float zl[52];

    const int b   = blockIdx.x;
    const int ta  = blockIdx.y * 16;
    const int nt0 = min(16, 63 - ta);
    const int tid = threadIdx.x;

    if (tid < NZ) zl[tid] = z[b * NZ + tid];
    __syncthreads();

    for (int i = tid; i < 336 * nt0; i += 512) {
        int c = i % 336, tt = i / 336;
        int row = c * 63 + ta + tt;
        const float* wr = dW + (size_t)row * NZ;
        float s = db[row];
        #pragma unroll
        for (int n = 0; n < NZ; ++n) s += zl[n] * wr[n];
        bufA[c * 17 + tt] = s;
    }
    __syncthreads();

    const float a0 = al0[0], a1 = al1[0], a2 = al2[0];

    for (int i = tid; i < 168 * 2 * nt0; i += 512) {
        int o = i % 168, tt1 = i / 168;
        int tt = tt1 >> 1, k = tt1 & 1;
        const float* wp = W0 + o * 2 + k;
        float s = 0.f;
        for (int c = 0; c < 336; ++c) s += bufA[c * 17 + tt] * wp[c * 336];
        float sc = g0[o] / sqrtf(v0[o] + EPSB);
        s = (s - m0[o]) * sc + bb0[o];
        s = (s >= 0.f) ? s : a0 * s;
        bufB[o * 33 + tt1] = s;
    }
    __syncthreads();

    for (int i = tid; i < 84 * 4 * nt0; i += 512) {
        int o = i % 84, tt2 = i / 84;
        int tt1 = tt2 >> 1, k = tt2 & 1;
        const float* wp = W1 + o * 2 + k;
        float s = 0.f;
        for (int c = 0; c < 168; ++c) s += bufB[c * 33 + tt1] * wp[c * 168];
        float sc = g1[o] / sqrtf(v1[o] + EPSB);
        s = (s - m1[o]) * sc + bb1[o];
        s = (s >= 0.f) ? s : a1 * s;
        bufA[o * 65 + tt2] = s;
    }
    __syncthreads();

    for (int i = tid; i < 42 * 8 * nt0; i += 512) {
        int o = i % 42, tt3 = i / 42;
        int tt2 = tt3 >> 1, k = tt3 & 1;
        const float* wp = W2 + o * 2 + k;
        float s = 0.f;
        for (int c = 0; c < 84; ++c) s += bufA[c * 65 + tt2] * wp[c * 84];
        float sc = g2[o] / sqrtf(v2[o] + EPSB);
        s = (s - m2[o]) * sc + bb2[o];
        s = (s >= 0.f) ? s : a2 * s;
        int t3 = 8 * ta + tt3;
        hseq[(size_t)t3 * (BATCH * 42) + b * 42 + o] = s;
    }
}

// ================= table: gi-contribution of one-hot px =====================
__global__ void table_kernel(const float* __restrict__ w_px, const float* __restrict__ b_px,
                             const float* __restrict__ w_ih, const float* __restrict__ b_ih,
                             float* __restrict__ table)
{
    int i = blockIdx.x * 256 + threadIdx.x;
    if (i >= 22 * 1536) return;
    int e = i / 1536, jg = i % 1536;
    const float* wih = w_ih + jg * 63 + 42;
    float s = b_ih[jg];
    #pragma unroll
    for (int jp = 0; jp < NC; ++jp) {
        float px = b_px[jp] + (e < NC ? w_px[jp * NC + e] : 0.f);
        s += px * wih[jp];
    }
    table[i] = s;
}

// ====== pack weights into MFMA B-fragment order, fp16 2-limb (lo x2048) =====
// whh: [g][nf(32)][kf(16)][lane(64)*8]; lane l supplies B[k=(l>>4)*8+e][n=l&15]
__global__ void pack_whh_kernel(const float* __restrict__ w_hh,
                                _Float16* __restrict__ pH, _Float16* __restrict__ pL)
{
    int i = blockIdx.x * 256 + threadIdx.x;
    if (i >= 3 * 32 * 16 * 512) return;
    int e = i & 7, l = (i >> 3) & 63, kf = (i >> 9) & 15, nf = (i >> 13) & 31, g = i >> 18;
    int n = nf * 16 + (l & 15);
    int k = kf * 32 + ((l >> 4) << 3) + e;
    float v = w_hh[(size_t)(g * GHID + n) * GHID + k];
    _Float16 hi, lo; split2(v, hi, lo);
    pH[i] = hi; pL[i] = lo;
}

__global__ void pack_wih_kernel(const float* __restrict__ w_ih,
                                _Float16* __restrict__ pH, _Float16* __restrict__ pL)
{
    int i = blockIdx.x * 256 + threadIdx.x;
    if (i >= 3 * 32 * 2 * 512) return;
    int e = i & 7, l = (i >> 3) & 63, kf = (i >> 9) & 1, nf = (i >> 10) & 31, g = i >> 15;
    int n = nf * 16 + (l & 15);
    int k = kf * 32 + ((l >> 4) << 3) + e;
    float v = (k < 42) ? w_ih[(size_t)(g * GHID + n) * 63 + k] : 0.f;
    _Float16 hi, lo; split2(v, hi, lo);
    pH[i] = hi; pL[i] = lo;
}

__global__ void pack_wout_kernel(const float* __restrict__ w_out,
                                 _Float16* __restrict__ pH, _Float16* __restrict__ pL)
{
    int i = blockIdx.x * 256 + threadIdx.x;
    if (i >= 2 * 16 * 512) return;
    int e = i & 7, l = (i >> 3) & 63, kf = (i >> 9) & 15, nf = i >> 13;
    int n = nf * 16 + (l & 15);
    int k = kf * 32 + ((l >> 4) << 3) + e;
    float v = (n < NC) ? w_out[(size_t)n * GHID + k] : 0.f;
    _Float16 hi, lo; split2(v, hi, lo);
    pH[i] = hi; pL[i] = lo;
}

// ==================== zero-communication 500-step decode ====================
// 256 INDEPENDENT blocks x 512 thr; block owns 8 batch rows for all 500 steps.
// h state: LDS fp16 2-limb, [2]-ping-pong [16 rows(8 real+8 zero-pad)][512],
// XOR-swizzled (k ^= (row&7)<<3, units of fp16 elems) -> 2-way-max bank use.
// hseq staged per-step into LDS by waves 2-7 while waves 0-1 do logits.
// Weights: packed global (L2-resident, read-only, ~3.6 MB/step/CU stream).
// No atomics, no barriers, no cross-block state. argmax once per row.
#define MFMA3(mainA, crossA, aH_, aL_, bH_, bL_)                                   \
    mainA  = __builtin_amdgcn_mfma_f32_16x16x32_f16(aH_, bH_, mainA, 0, 0, 0);     \
    crossA = __builtin_amdgcn_mfma_f32_16x16x32_f16(aH_, bL_, crossA, 0, 0, 0);    \
    crossA = __builtin_amdgcn_mfma_f32_16x16x32_f16(aL_, bH_, crossA, 0, 0, 0);

__device__ __forceinline__ int hswz(int row, int k) {    // element index in [16][512]
    return row * 512 + (k ^ ((row & 7) << 3));
}
__device__ __forceinline__ int tswz(int row, int k) {    // element index in [16][64]
    return row * 64 + (k ^ ((row & 7) << 3));
}

__global__ __launch_bounds__(512, 1) void gru_rows(
    const float* __restrict__ hseq,
    const float* __restrict__ table,
    const _Float16* __restrict__ whhH, const _Float16* __restrict__ whhL,
    const _Float16* __restrict__ wihH, const _Float16* __restrict__ wihL,
    const _Float16* __restrict__ woH,  const _Float16* __restrict__ woL,
    const float* __restrict__ b_hh, const float* __restrict__ b_out,
    float* __restrict__ out)
{
    __shared__ _Float16 hHi[2][16 * 512];
    __shared__ _Float16 hLo[2][16 * 512];
    __shared__ _Float16 tHi[2][16 * 64];
    __shared__ _Float16 tLo[2][16 * 64];
    __shared__ float    lgbuf[8][32];
    __shared__ int      idx_l[8];

    const int tid  = threadIdx.x;
    const int l    = tid & 63, wv = tid >> 6;
    const int lrow = l & 15, lk = (l >> 4) << 3;
    const int row0 = blockIdx.x * 8;

    // ---- prologue: zero LDS state, stage hseq[0], idx = NC -----------------
    for (int i = tid; i < 16 * 512; i += 512) {
        hHi[0][i] = (_Float16)0.f; hHi[1][i] = (_Float16)0.f;
        hLo[0][i] = (_Float16)0.f; hLo[1][i] = (_Float16)0.f;
    }
    for (int i = tid; i < 16 * 64; i += 512) {
        tHi[0][i] = (_Float16)0.f; tHi[1][i] = (_Float16)0.f;
        tLo[0][i] = (_Float16)0.f; tLo[1][i] = (_Float16)0.f;
    }
    if (tid < 8) idx_l[tid] = NC;
    __syncthreads();
    if (tid < 336) {
        int r = tid / 42, k = tid % 42;
        float f = hseq[(size_t)(row0 + r) * 42 + k];
        _Float16 hi, lo; split2(f, hi, lo);
        int o = tswz(r, k);
        tHi[0][o] = hi; tLo[0][o] = lo;
    }
    __syncthreads();

    for (int t = 0; t < REAL_NL; ++t) {
        const int pp = t & 1, pn = pp ^ 1;

        // ---------- S0: gates (4 col-jobs per wave, 32 jobs = 512 cols) ------
        #pragma unroll
        for (int jj = 0; jj < 4; ++jj) {
            const int nf = wv + jj * 8;
            // streams: 0=r(H+I) 1=z(H+I) 2=IN 3=HN
            f32x4 aM[4], aX[4];
            #pragma unroll
            for (int s = 0; s < 4; ++s) { aM[s] = (f32x4)0.f; aX[s] = (f32x4)0.f; }

            // H part: K = 512
            for (int kf = 0; kf < 16; ++kf) {
                int ao = hswz(lrow, kf * 32 + lk);
                half8 aH = *(const half8*)(&hHi[pp][ao]);
                half8 aL = *(const half8*)(&hLo[pp][ao]);
                #pragma unroll
                for (int g = 0; g < 3; ++g) {
                    size_t bo = ((size_t)((g * 32 + nf) * 16 + kf) << 9) + (l << 3);
                    half8 bH = *(const half8*)(whhH + bo);
                    half8 bL = *(const half8*)(whhL + bo);
                    const int s = (g == 2) ? 3 : g;
                    MFMA3(aM[s], aX[s], aH, aL, bH, bL);
                }
            }
            // I part: K = 64 (42 real, zero-padded) from staged hseq LDS
            #pragma unroll
            for (int kf = 0; kf < 2; ++kf) {
                int ao = tswz(lrow, kf * 32 + lk);
                half8 aH = *(const half8*)(&tHi[pp][ao]);
                half8 aL = *(const half8*)(&tLo[pp][ao]);
                #pragma unroll
                for (int g = 0; g < 3; ++g) {
                    size_t bo = ((size_t)((g * 32 + nf) * 2 + kf) << 9) + (l << 3);
                    half8 bH = *(const half8*)(wihH + bo);
                    half8 bL = *(const half8*)(wihL + bo);
                    const int s = (g == 2) ? 2 : g;
                    MFMA3(aM[s], aX[s], aH, aL, bH, bL);
                }
            }
            // epilogue: D row=(l>>4)*4+r, col=l&15; real rows are 0..7 (l<32)
            if (l < 32) {
                const int c = nf * 16 + lrow;
                const float bhr = b_hh[c], bhz = b_hh[GHID + c], bhn = b_hh[2 * GHID + c];
                #pragma unroll
                for (int r = 0; r < 4; ++r) {
                    int row = ((l >> 4) << 2) + r;          // 0..7
                    const float* tb = table + idx_l[row] * 1536;
                    float rv  = aM[0][r] + aX[0][r] * INV_LO + bhr + tb[c];
                    float zv  = aM[1][r] + aX[1][r] * INV_LO + bhz + tb[GHID + c];
                    float inp = aM[2][r] + aX[2][r] * INV_LO + tb[2 * GHID + c];
                    float hnp = aM[3][r] + aX[3][r] * INV_LO + bhn;
                    float rg = 1.f / (1.f + expf(-rv));
                    float zg = 1.f / (1.f + expf(-zv));
                    float ng = tanhf(inp + rg * hnp);
                    int ho = hswz(row, c);
                    float hpv = (float)hHi[pp][ho] + (float)hLo[pp][ho] * INV_LO;
                    float hnv = (1.f - zg) * ng + zg * hpv;
                    _Float16 hi, lo; split2(hnv, hi, lo);
                    hHi[pn][ho] = hi; hLo[pn][ho] = lo;
                }
            }
        }
        __syncthreads();   // h[t+1] complete in plane pn

        // ---------- S1: logits on h_new (waves 0-1) || stage hseq[t+1] -------
        if (wv < 2) {
            f32x4 lM = (f32x4)0.f, lX = (f32x4)0.f;
            for (int kf = 0; kf < 16; ++kf) {
                int ao = hswz(lrow, kf * 32 + lk);
                half8 aH = *(const half8*)(&hHi[pn][ao]);
                half8 aL = *(const half8*)(&hLo[pn][ao]);
                size_t bo = ((size_t)(wv * 16 + kf) << 9) + (l << 3);
                half8 bH = *(const half8*)(woH + bo);
                half8 bL = *(const half8*)(woL + bo);
                MFMA3(lM, lX, aH, aL, bH, bL);
            }
            if (l < 32) {
                int col = wv * 16 + lrow;
                float bias = (col < NC) ? b_out[col] : 0.f;
                #pragma unroll
                for (int r = 0; r < 4; ++r) {
                    int row = ((l >> 4) << 2) + r;
                    lgbuf[row][col] = lM[r] + lX[r] * INV_LO + bias;
                }
            }
        } else {
            int s = tid - 128;
            if (s < 336) {
                int r = s / 42, k = s % 42;
                float f = hseq[(size_t)(t + 1) * (BATCH * 42) + (size_t)(row0 + r) * 42 + k];
                _Float16 hi, lo; split2(f, hi, lo);
                int o = tswz(r, k);
                tHi[pn][o] = hi; tLo[pn][o] = lo;
            }
        }
        __syncthreads();

        // ---------- S2: argmax (first-max) + out[t] ---------------------------
        if (tid < 8) {
            float best = lgbuf[tid][0]; int bi = 0;
            #pragma unroll
            for (int c = 1; c < NC; ++c) {
                float v = lgbuf[tid][c];
                if (v > best) { best = v; bi = c; }   // strict > keeps first max
            }
            idx_l[tid] = bi;
            float* op = out + (size_t)(row0 + tid) * (REAL_NL * NC) + (size_t)t * NC;
            #pragma unroll
            for (int c = 0; c < NC; ++c) op[c] = lgbuf[tid][c];
        }
        __syncthreads();
    }
}

// ============================================================================
extern "C" void kernel_launch(void* const* d_in, const int* in_sizes, int n_in,
                              void* d_out, int out_size, void* d_ws, size_t ws_size,
                              hipStream_t stream)
{
    const float* z    = (const float*)d_in[1];
    const float* dW   = (const float*)d_in[3];
    const float* db   = (const float*)d_in[4];
    const float* W0   = (const float*)d_in[5];
    const float* g0   = (const float*)d_in[6];
    const float* bb0  = (const float*)d_in[7];
    const float* m0   = (const float*)d_in[8];
    const float* v0   = (const float*)d_in[9];
    const float* al0  = (const float*)d_in[10];
    const float* W1   = (const float*)d_in[11];
    const float* g1   = (const float*)d_in[12];
    const float* bb1  = (const float*)d_in[13];
    const float* m1   = (const float*)d_in[14];
    const float* v1   = (const float*)d_in[15];
    const float* al1  = (const float*)d_in[16];
    const float* W2   = (const float*)d_in[17];
    const float* g2   = (const float*)d_in[18];
    const float* bb2  = (const float*)d_in[19];
    const float* m2   = (const float*)d_in[20];
    const float* v2   = (const float*)d_in[21];
    const float* al2  = (const float*)d_in[22];
    const float* w_px = (const float*)d_in[23];
    const float* b_px = (const float*)d_in[24];
    const float* w_ih = (const float*)d_in[25];
    const float* w_hh = (const float*)d_in[26];
    const float* b_ih = (const float*)d_in[27];
    const float* b_hh = (const float*)d_in[28];
    const float* w_out= (const float*)d_in[29];
    const float* b_out= (const float*)d_in[30];
    float* out = (float*)d_out;

    // ws: hseq(f32) | whh H/L | wih H/L | wo H/L | table
    float* ws = (float*)d_ws;
    float* hseq = ws;                                            // 504*2048*42 f32
    _Float16* whhH = (_Float16*)(hseq + (size_t)NLFULL * BATCH * 42);
    _Float16* whhL = whhH + 3 * 32 * 16 * 512;
    _Float16* wihH = whhL + 3 * 32 * 16 * 512;
    _Float16* wihL = wihH + 3 * 32 * 2 * 512;
    _Float16* woH  = wihL + 3 * 32 * 2 * 512;
    _Float16* woL  = woH + 2 * 16 * 512;
    float* table = (float*)(woL + 2 * 16 * 512);                 // 22*1536

    upsample_kernel<<<dim3(BATCH, 4), 512, 0, stream>>>(
        z, dW, db,
        W0, g0, bb0, m0, v0, al0,
        W1, g1, bb1, m1, v1, al1,
        W2, g2, bb2, m2, v2, al2,
        hseq);

    table_kernel<<<(22 * 1536 + 255) / 256, 256, 0, stream>>>(w_px, b_px, w_ih, b_ih, table);
    pack_whh_kernel<<<(3 * 32 * 16 * 512 + 255) / 256, 256, 0, stream>>>(w_hh, whhH, whhL);
    pack_wih_kernel<<<(3 * 32 * 2 * 512 + 255) / 256, 256, 0, stream>>>(w_ih, wihH, wihL);
    pack_wout_kernel<<<(2 * 16 * 512 + 255) / 256, 256, 0, stream>>>(w_out, woH, woL);

    gru_rows<<<256, 512, 0, stream>>>(
        hseq, table, whhH, whhL, wihH, wihL, woH, woL, b_hh, b_out, out);
}

// Round 9
// 39545.145 us; speedup vs baseline: 2.9052x; 2.9052x over previous
//
#include <hip/hip_runtime.h>
#include <math.h>

#define NLFULL 504
#define REAL_NL 500
#define BATCH 2048
#define NZ 50
#define NC 21
#define GHID 512
#define EPSB 1e-5f
#define LO_SCALE 2048.0f
#define INV_LO (1.0f / 2048.0f)

typedef __attribute__((ext_vector_type(4))) float f32x4;
typedef __attribute__((ext_vector_type(8))) _Float16 half8;

__device__ __forceinline__ void split2(float x, _Float16& hi, _Float16& lo) {
    hi = (_Float16)x;
    lo = (_Float16)((x - (float)hi) * LO_SCALE);
}

// =============================== upsample ==================================
__global__ __launch_bounds__(512) void upsample_kernel(
    const float* __restrict__ z, const float* __restrict__ dW, const float* __restrict__ db,
    const float* __restrict__ W0, const float* __restrict__ g0, const float* __restrict__ bb0,
    const float* __restrict__ m0, const float* __restrict__ v0, const float* __restrict__ al0,
    const float* __restrict__ W1, const float* __restrict__ g1, const float* __restrict__ bb1,
    const float* __restrict__ m1, const float* __restrict__ v1, const float* __restrict__ al1,
    const float* __restrict__ W2, const float* __restrict__ g2, const float* __restrict__ bb2,
    const float* __restrict__ m2, const float* __restrict__ v2, const float* __restrict__ al2,
    float* __restrict__ hseq)
{
    __shared__ float bufA[5712];
    __shared__ float bufB[5544];
    __shared__ float zl[52];

    const int b   = blockIdx.x;
    const int ta  = blockIdx.y * 16;
    const int nt0 = min(16, 63 - ta);
    const int tid = threadIdx.x;

    if (tid < NZ) zl[tid] = z[b * NZ + tid];
    __syncthreads();

    for (int i = tid; i < 336 * nt0; i += 512) {
        int c = i % 336, tt = i / 336;
        int row = c * 63 + ta + tt;
        const float* wr = dW + (size_t)row * NZ;
        float s = db[row];
        #pragma unroll
        for (int n = 0; n < NZ; ++n) s += zl[n] * wr[n];
        bufA[c * 17 + tt] = s;
    }
    __syncthreads();

    const float a0 = al0[0], a1 = al1[0], a2 = al2[0];

    for (int i = tid; i < 168 * 2 * nt0; i += 512) {
        int o = i % 168, tt1 = i / 168;
        int tt = tt1 >> 1, k = tt1 & 1;
        const float* wp = W0 + o * 2 + k;
        float s = 0.f;
        for (int c = 0; c < 336; ++c) s += bufA[c * 17 + tt] * wp[c * 336];
        float sc = g0[o] / sqrtf(v0[o] + EPSB);
        s = (s - m0[o]) * sc + bb0[o];
        s = (s >= 0.f) ? s : a0 * s;
        bufB[o * 33 + tt1] = s;
    }
    __syncthreads();

    for (int i = tid; i < 84 * 4 * nt0; i += 512) {
        int o = i % 84, tt2 = i / 84;
        int tt1 = tt2 >> 1, k = tt2 & 1;
        const float* wp = W1 + o * 2 + k;
        float s = 0.f;
        for (int c = 0; c < 168; ++c) s += bufB[c * 33 + tt1] * wp[c * 168];
        float sc = g1[o] / sqrtf(v1[o] + EPSB);
        s = (s - m1[o]) * sc + bb1[o];
        s = (s >= 0.f) ? s : a1 * s;
        bufA[o * 65 + tt2] = s;
    }
    __syncthreads();

    for (int i = tid; i < 42 * 8 * nt0; i += 512) {
        int o = i % 42, tt3 = i / 42;
        int tt2 = tt3 >> 1, k = tt3 & 1;
        const float* wp = W2 + o * 2 + k;
        float s = 0.f;
        for (int c = 0; c < 84; ++c) s += bufA[c * 65 + tt2] * wp[c * 84];
        float sc = g2[o] / sqrtf(v2[o] + EPSB);
        s = (s - m2[o]) * sc + bb2[o];
        s = (s >= 0.f) ? s : a2 * s;
        int t3 = 8 * ta + tt3;
        hseq[(size_t)t3 * (BATCH * 42) + b * 42 + o] = s;
    }
}

// ================= table: gi-contribution of one-hot px =====================
__global__ void table_kernel(const float* __restrict__ w_px, const float* __restrict__ b_px,
                             const float* __restrict__ w_ih, const float* __restrict__ b_ih,
                             float* __restrict__ table)
{
    int i = blockIdx.x * 256 + threadIdx.x;
    if (i >= 22 * 1536) return;
    int e = i / 1536, jg = i % 1536;
    const float* wih = w_ih + jg * 63 + 42;
    float s = b_ih[jg];
    #pragma unroll
    for (int jp = 0; jp < NC; ++jp) {
        float px = b_px[jp] + (e < NC ? w_px[jp * NC + e] : 0.f);
        s += px * wih[jp];
    }
    table[i] = s;
}

// ====== pack weights into MFMA B-fragment order, fp16 2-limb (lo x2048) =====
// whh: [g][nf(32)][kf(16)][lane(64)*8]; lane l supplies B[k=(l>>4)*8+e][n=l&15]
__global__ void pack_whh_kernel(const float* __restrict__ w_hh,
                                _Float16* __restrict__ pH, _Float16* __restrict__ pL)
{
    int i = blockIdx.x * 256 + threadIdx.x;
    if (i >= 3 * 32 * 16 * 512) return;
    int e = i & 7, l = (i >> 3) & 63, kf = (i >> 9) & 15, nf = (i >> 13) & 31, g = i >> 18;
    int n = nf * 16 + (l & 15);
    int k = kf * 32 + ((l >> 4) << 3) + e;
    float v = w_hh[(size_t)(g * GHID + n) * GHID + k];
    _Float16 hi, lo; split2(v, hi, lo);
    pH[i] = hi; pL[i] = lo;
}

__global__ void pack_wih_kernel(const float* __restrict__ w_ih,
                                _Float16* __restrict__ pH, _Float16* __restrict__ pL)
{
    int i = blockIdx.x * 256 + threadIdx.x;
    if (i >= 3 * 32 * 2 * 512) return;
    int e = i & 7, l = (i >> 3) & 63, kf = (i >> 9) & 1, nf = (i >> 10) & 31, g = i >> 15;
    int n = nf * 16 + (l & 15);
    int k = kf * 32 + ((l >> 4) << 3) + e;
    float v = (k < 42) ? w_ih[(size_t)(g * GHID + n) * 63 + k] : 0.f;
    _Float16 hi, lo; split2(v, hi, lo);
    pH[i] = hi; pL[i] = lo;
}

__global__ void pack_wout_kernel(const float* __restrict__ w_out,
                                 _Float16* __restrict__ pH, _Float16* __restrict__ pL)
{
    int i = blockIdx.x * 256 + threadIdx.x;
    if (i >= 2 * 16 * 512) return;
    int e = i & 7, l = (i >> 3) & 63, kf = (i >> 9) & 15, nf = i >> 13;
    int n = nf * 16 + (l & 15);
    int k = kf * 32 + ((l >> 4) << 3) + e;
    float v = (n < NC) ? w_out[(size_t)n * GHID + k] : 0.f;
    _Float16 hi, lo; split2(v, hi, lo);
    pH[i] = hi; pL[i] = lo;
}

// ===================== init h0 (fp16 2-limb planes) =========================
__global__ void init_kernel(_Float16* __restrict__ hH, _Float16* __restrict__ hL)
{
    int i = blockIdx.x * 256 + threadIdx.x;
    if (i < BATCH * GHID) { hH[i] = (_Float16)0.f; hL[i] = (_Float16)0.f; }
}

// ==================== fused per-step kernel (re-tiled) ======================
// grid (8 n-slices, 32 m-tiles) = 256 blocks, 512 thr (8 waves).
// Block tile: 64 rows x 64 cols x 3 gates. bid%8 = n-slice = XCD heuristic ->
// per-XCD weight slice (whh 393KB + wih 49KB + wo 65KB + table 135KB ~ 0.65MB)
// stays L2-resident across all 501 dispatches (clean lines persist).
// Wave layout: af = wv&3 (16-row A-frag), nf-pair = (wv>>2)*2 (gates);
// logits: af = wv&3, wo-nf = wv>>2. Phase1 logits(h_prev)+argmax (redundant
// x8 across n-slices, bit-identical); phase2 gates -> h_new.
#define MFMA3(mainA, crossA, aH_, aL_, bH_, bL_)                                   \
    mainA  = __builtin_amdgcn_mfma_f32_16x16x32_f16(aH_, bH_, mainA, 0, 0, 0);     \
    crossA = __builtin_amdgcn_mfma_f32_16x16x32_f16(aH_, bL_, crossA, 0, 0, 0);    \
    crossA = __builtin_amdgcn_mfma_f32_16x16x32_f16(aL_, bH_, crossA, 0, 0, 0);

__global__ __launch_bounds__(512) void gru_step(
    const _Float16* __restrict__ hpH, const _Float16* __restrict__ hpL,
    const float* __restrict__ ht,          // hseq + t*B*42
    const float* __restrict__ table,
    const _Float16* __restrict__ whhH, const _Float16* __restrict__ whhL,
    const _Float16* __restrict__ wihH, const _Float16* __restrict__ wihL,
    const float* __restrict__ b_hh,
    const _Float16* __restrict__ woH, const _Float16* __restrict__ woL,
    const float* __restrict__ b_out,
    float* __restrict__ out, int t,
    _Float16* __restrict__ hnH, _Float16* __restrict__ hnL)
{
    __shared__ float lg[64][33];
    __shared__ int   idx_lds[64];

    const int tid  = threadIdx.x;
    const int l    = tid & 63;
    const int wv   = tid >> 6;            // 0..7
    const int m0   = blockIdx.y * 64;
    const int lrow = l & 15;
    const int lk   = (l >> 4) << 3;
    const int af   = wv & 3;              // 16-row A-frag index

    const size_t arow = (size_t)(m0 + af * 16 + lrow) * GHID + lk;

    // ---------------- phase 1: logits + argmax on h_prev --------------------
    if (t > 0) {
        const int nfl = wv >> 2;          // wo n-frag 0..1
        f32x4 accM = (f32x4)0.f, accX = (f32x4)0.f;
        for (int kf = 0; kf < 16; ++kf) {
            half8 aH = *(const half8*)(hpH + arow + kf * 32);
            half8 aL = *(const half8*)(hpL + arow + kf * 32);
            size_t bo = ((size_t)(nfl * 16 + kf) << 9) + (l << 3);
            half8 bH = *(const half8*)(woH + bo);
            half8 bL = *(const half8*)(woL + bo);
            MFMA3(accM, accX, aH, aL, bH, bL);
        }
        int col = nfl * 16 + lrow;
        float bias = (col < NC) ? b_out[col] : 0.f;
        #pragma unroll
        for (int r = 0; r < 4; ++r) {
            int row = af * 16 + ((l >> 4) << 2) + r;
            lg[row][col] = accM[r] + accX[r] * INV_LO + bias;
        }
    }
    __syncthreads();
    if (tid < 64) {
        int bi = NC;                      // t==0: zeros-x1h table entry
        if (t > 0) {
            float best = lg[tid][0]; bi = 0;
            #pragma unroll
            for (int c = 1; c < NC; ++c) {
                float v = lg[tid][c];
                if (v > best) { best = v; bi = c; }   // strict > keeps first max
            }
            if (blockIdx.x == 0) {
                float* op = out + (size_t)(m0 + tid) * (REAL_NL * NC)
                                + (size_t)(t - 1) * NC;
                #pragma unroll
                for (int c = 0; c < NC; ++c) op[c] = lg[tid][c];
            }
        }
        idx_lds[tid] = bi;
    }
    __syncthreads();

    if (t >= REAL_NL) return;    // t == REAL_NL: logits-only launch

    // ---------------- phase 2: GRU gates ------------------------------------
    const int nfb = (wv >> 2) * 2;                // local nf base 0/2
    // streams: 0=r, 1=z, 2=in(I part), 3=hn(H part)
    f32x4 gM[4][2], gX[4][2];
    #pragma unroll
    for (int s = 0; s < 4; ++s)
        #pragma unroll
        for (int cc = 0; cc < 2; ++cc) { gM[s][cc] = (f32x4)0.f; gX[s][cc] = (f32x4)0.f; }

    // H part: K = 512 = 16 k-frags
    for (int kf = 0; kf < 16; ++kf) {
        half8 aH = *(const half8*)(hpH + arow + kf * 32);
        half8 aL = *(const half8*)(hpL + arow + kf * 32);
        #pragma unroll
        for (int g = 0; g < 3; ++g) {
            #pragma unroll
            for (int cc = 0; cc < 2; ++cc) {
                int nfg = blockIdx.x * 4 + nfb + cc;
                size_t bo = ((size_t)((g * 32 + nfg) * 16 + kf) << 9) + (l << 3);
                half8 bH = *(const half8*)(whhH + bo);
                half8 bL = *(const half8*)(whhL + bo);
                const int s = (g == 2) ? 3 : g;
                MFMA3(gM[s][cc], gX[s][cc], aH, aL, bH, bL);
            }
        }
    }

    // I part: K = 42 (2 k-frags, on-the-fly fp32 -> 2-limb split)
    #pragma unroll
    for (int kf = 0; kf < 2; ++kf) {
        half8 aH, aL;
        const float* rp = ht + (size_t)(m0 + af * 16 + lrow) * 42;
        #pragma unroll
        for (int e = 0; e < 8; ++e) {
            int k = kf * 32 + lk + e;
            float f = (k < 42) ? rp[k] : 0.f;
            _Float16 hi, lo; split2(f, hi, lo);
            aH[e] = hi; aL[e] = lo;
        }
        #pragma unroll
        for (int g = 0; g < 3; ++g) {
            #pragma unroll
            for (int cc = 0; cc < 2; ++cc) {
                int nfg = blockIdx.x * 4 + nfb + cc;
                size_t bo = ((size_t)((g * 32 + nfg) * 2 + kf) << 9) + (l << 3);
                half8 bH = *(const half8*)(wihH + bo);
                half8 bL = *(const half8*)(wihL + bo);
                const int s = (g == 2) ? 2 : g;
                MFMA3(gM[s][cc], gX[s][cc], aH, aL, bH, bL);
            }
        }
    }

    // epilogue: D layout row=(l>>4)*4+r, col=l&15
    #pragma unroll
    for (int cc = 0; cc < 2; ++cc) {
        int nfg = blockIdx.x * 4 + nfb + cc;
        int c = nfg * 16 + lrow;
        float bhr = b_hh[c], bhz = b_hh[GHID + c], bhn = b_hh[2 * GHID + c];
        #pragma unroll
        for (int r = 0; r < 4; ++r) {
            int lm = af * 16 + ((l >> 4) << 2) + r;   // local row 0..63
            int m = m0 + lm;
            const float* tb = table + idx_lds[lm] * 1536;
            float rv  = gM[0][cc][r] + gX[0][cc][r] * INV_LO + bhr + tb[c];
            float zv  = gM[1][cc][r] + gX[1][cc][r] * INV_LO + bhz + tb[GHID + c];
            float inp = gM[2][cc][r] + gX[2][cc][r] * INV_LO + tb[2 * GHID + c];
            float hnp = gM[3][cc][r] + gX[3][cc][r] * INV_LO + bhn;
            float rg = 1.f / (1.f + expf(-rv));
            float zg = 1.f / (1.f + expf(-zv));
            float ng = tanhf(inp + rg * hnp);
            size_t off = (size_t)m * GHID + c;
            float hpv = (float)hpH[off] + (float)hpL[off] * INV_LO;
            float hnv = (1.f - zg) * ng + zg * hpv;
            _Float16 hi, lo; split2(hnv, hi, lo);
            hnH[off] = hi; hnL[off] = lo;
        }
    }
}

// ============================================================================
extern "C" void kernel_launch(void* const* d_in, const int* in_sizes, int n_in,
                              void* d_out, int out_size, void* d_ws, size_t ws_size,
                              hipStream_t stream)
{
    const float* z    = (const float*)d_in[1];
    const float* dW   = (const float*)d_in[3];
    const float* db   = (const float*)d_in[4];
    const float* W0   = (const float*)d_in[5];
    const float* g0   = (const float*)d_in[6];
    const float* bb0  = (const float*)d_in[7];
    const float* m0   = (const float*)d_in[8];
    const float* v0   = (const float*)d_in[9];
    const float* al0  = (const float*)d_in[10];
    const float* W1   = (const float*)d_in[11];
    const float* g1   = (const float*)d_in[12];
    const float* bb1  = (const float*)d_in[13];
    const float* m1   = (const float*)d_in[14];
    const float* v1   = (const float*)d_in[15];
    const float* al1  = (const float*)d_in[16];
    const float* W2   = (const float*)d_in[17];
    const float* g2   = (const float*)d_in[18];
    const float* bb2  = (const float*)d_in[19];
    const float* m2   = (const float*)d_in[20];
    const float* v2   = (const float*)d_in[21];
    const float* al2  = (const float*)d_in[22];
    const float* w_px = (const float*)d_in[23];
    const float* b_px = (const float*)d_in[24];
    const float* w_ih = (const float*)d_in[25];
    const float* w_hh = (const float*)d_in[26];
    const float* b_ih = (const float*)d_in[27];
    const float* b_hh = (const float*)d_in[28];
    const float* w_out= (const float*)d_in[29];
    const float* b_out= (const float*)d_in[30];
    float* out = (float*)d_out;

    // ws: hseq(f32) | hA H/L | hB H/L | whh H/L | wih H/L | wo H/L | table
    float* ws = (float*)d_ws;
    float* hseq = ws;                                            // 504*2048*42 f32
    _Float16* hAH = (_Float16*)(hseq + (size_t)NLFULL * BATCH * 42);
    _Float16* hAL = hAH + (size_t)BATCH * GHID;
    _Float16* hBH = hAL + (size_t)BATCH * GHID;
    _Float16* hBL = hBH + (size_t)BATCH * GHID;
    _Float16* whhH = hBL + (size_t)BATCH * GHID;                 // 3*32*16*512
    _Float16* whhL = whhH + 3 * 32 * 16 * 512;
    _Float16* wihH = whhL + 3 * 32 * 16 * 512;                   // 3*32*2*512
    _Float16* wihL = wihH + 3 * 32 * 2 * 512;
    _Float16* woH  = wihL + 3 * 32 * 2 * 512;                    // 2*16*512
    _Float16* woL  = woH + 2 * 16 * 512;
    float* table = (float*)(woL + 2 * 16 * 512);                 // 22*1536

    upsample_kernel<<<dim3(BATCH, 4), 512, 0, stream>>>(
        z, dW, db,
        W0, g0, bb0, m0, v0, al0,
        W1, g1, bb1, m1, v1, al1,
        W2, g2, bb2, m2, v2, al2,
        hseq);

    table_kernel<<<(22 * 1536 + 255) / 256, 256, 0, stream>>>(w_px, b_px, w_ih, b_ih, table);
    pack_whh_kernel<<<(3 * 32 * 16 * 512 + 255) / 256, 256, 0, stream>>>(w_hh, whhH, whhL);
    pack_wih_kernel<<<(3 * 32 * 2 * 512 + 255) / 256, 256, 0, stream>>>(w_ih, wihH, wihL);
    pack_wout_kernel<<<(2 * 16 * 512 + 255) / 256, 256, 0, stream>>>(w_out, woH, woL);
    init_kernel<<<(BATCH * GHID + 255) / 256, 256, 0, stream>>>(hAH, hAL);

    // t = 0..REAL_NL: step t does logits(h[t-1]) -> out[t-1], then gates -> h[t]
    for (int t = 0; t <= REAL_NL; ++t) {
        const _Float16* pH = (t & 1) ? hBH : hAH;
        const _Float16* pL = (t & 1) ? hBL : hAL;
        _Float16* nH = (t & 1) ? hAH : hBH;
        _Float16* nL = (t & 1) ? hAL : hBL;
        gru_step<<<dim3(8, 32), 512, 0, stream>>>(
            pH, pL, hseq + (size_t)t * BATCH * 42, table,
            whhH, whhL, wihH, wihL, b_hh,
            woH, woL, b_out, out, t, nH, nL);
    }
}